// Round 1
// baseline (38.548 us; speedup 1.0000x reference)
//
#include <hip/hip_runtime.h>

// Problem constants (fixed by setup_inputs):
//   query:          [N=8, C=640, H=48, W=48] f32
//   dynamic_filter: [N=8, H*W=2304, K=9, 1]  f32
//   out1 = relu(per-pixel 3x3 dyn conv, filter shared over C): [8,640,48,48] f32
//   out2 = zeros like dynamic_filter
#define N_   8
#define C_   640
#define H_   48
#define W_   48
#define K_   9
#define TDIM 16          // 16x16 spatial tile, 3x3 tiles cover 48x48 exactly
#define PATCH 18         // tile + 1-halo each side
#define PSZ (PATCH*PATCH)// 324
#define CPB 40           // channels per block  (640/40 = 16 chunks)
#define CPG 4            // channels staged per LDS group

__global__ __launch_bounds__(256) void dynconv_kernel(
    const float* __restrict__ q,
    const float* __restrict__ df,
    float* __restrict__ out)
{
    __shared__ float sp[CPG][PSZ];

    const int tid  = threadIdx.x;
    const int b    = blockIdx.x;
    const int tile = b % 9;
    const int n    = (b / 9) % N_;
    const int cc   = b / (9 * N_);
    const int c0   = cc * CPB;

    const int th = (tile / 3) * TDIM;
    const int tw = (tile % 3) * TDIM;
    const int tx = tid & 15;
    const int ty = tid >> 4;
    const int h  = th + ty;
    const int w  = tw + tx;

    // --- per-pixel 3x3 filter taps: reused across all channels ---
    float f[K_];
    const float* dfp = df + ((size_t)(n * (H_ * W_) + h * W_ + w)) * K_;
#pragma unroll
    for (int k = 0; k < K_; ++k) f[k] = dfp[k];

    // --- precompute the (<=2) staging offsets this thread owns ---
    // off == -1 : slot exists but out-of-bounds (store 0)
    // off == -2 : no slot for this thread
    int off1, off2;
    {
        int idx = tid;
        int py = idx / PATCH, px = idx - py * PATCH;
        int gy = th - 1 + py, gx = tw - 1 + px;
        off1 = (gy >= 0 && gy < H_ && gx >= 0 && gx < W_) ? (gy * W_ + gx) : -1;

        idx = tid + 256;
        if (idx < PSZ) {
            py = idx / PATCH; px = idx - py * PATCH;
            gy = th - 1 + py; gx = tw - 1 + px;
            off2 = (gy >= 0 && gy < H_ && gx >= 0 && gx < W_) ? (gy * W_ + gx) : -1;
        } else {
            off2 = -2;
        }
    }

    const size_t plane = (size_t)H_ * W_;
    const float* qn = q  + (size_t)n * C_ * plane;
    float*       on = out + (size_t)n * C_ * plane;

    // --- prefetch first channel group ---
    float v1[CPG], v2[CPG];
#pragma unroll
    for (int ch = 0; ch < CPG; ++ch) {
        const float* qc = qn + (size_t)(c0 + ch) * plane;
        v1[ch] = (off1 >= 0) ? qc[off1] : 0.f;
        if (off2 != -2) v2[ch] = (off2 >= 0) ? qc[off2] : 0.f;
    }

    for (int cg = 0; cg < CPB; cg += CPG) {
        __syncthreads();   // previous group's readers done
#pragma unroll
        for (int ch = 0; ch < CPG; ++ch) {
            sp[ch][tid] = v1[ch];
            if (off2 != -2) sp[ch][tid + 256] = v2[ch];
        }
        __syncthreads();

        // prefetch next group while we compute this one
        if (cg + CPG < CPB) {
#pragma unroll
            for (int ch = 0; ch < CPG; ++ch) {
                const float* qc = qn + (size_t)(c0 + cg + CPG + ch) * plane;
                v1[ch] = (off1 >= 0) ? qc[off1] : 0.f;
                if (off2 != -2) v2[ch] = (off2 >= 0) ? qc[off2] : 0.f;
            }
        }

        // compute + store current group
#pragma unroll
        for (int ch = 0; ch < CPG; ++ch) {
            float acc = 0.f;
#pragma unroll
            for (int dy = 0; dy < 3; ++dy)
#pragma unroll
                for (int dx = 0; dx < 3; ++dx)
                    acc = fmaf(sp[ch][(ty + dy) * PATCH + (tx + dx)],
                               f[dy * 3 + dx], acc);
            on[(size_t)(c0 + cg + ch) * plane + h * W_ + w] = fmaxf(acc, 0.f);
        }
    }
}

extern "C" void kernel_launch(void* const* d_in, const int* in_sizes, int n_in,
                              void* d_out, int out_size, void* d_ws, size_t ws_size,
                              hipStream_t stream)
{
    const float* q  = (const float*)d_in[0];
    const float* df = (const float*)d_in[1];
    float* out = (float*)d_out;

    const size_t out1_elems = (size_t)N_ * C_ * H_ * W_;   // 11,796,480
    const size_t out2_elems = (size_t)N_ * H_ * W_ * K_;   //    165,888

    const int blocks = N_ * 9 * (C_ / CPB);                // 8*9*16 = 1152
    dynconv_kernel<<<blocks, 256, 0, stream>>>(q, df, out);

    // second output: zeros like dynamic_filter
    hipMemsetAsync((char*)d_out + out1_elems * sizeof(float), 0,
                   out2_elems * sizeof(float), stream);
}

// Round 2
// 30.005 us; speedup vs baseline: 1.2847x; 1.2847x over previous
//
#include <hip/hip_runtime.h>

// query:          [N=8, C=640, H=48, W=48] f32
// dynamic_filter: [N=8, 2304, 9, 1] f32   (per-pixel 3x3 taps, shared over C)
// out1 = relu(dynamic 3x3 conv): [8,640,48,48] f32
// out2 = zeros_like(dynamic_filter)
#define N_   8
#define C_   640
#define H_   48
#define W_   48
#define K_   9
#define CH   10                 // channels per thread -> 64 chunks
#define NCHUNK (C_ / CH)        // 64
#define BLK  576                // 48 rows x 12 float4-strips = one plane
#define OUT1_ELEMS ((size_t)N_ * C_ * H_ * W_)      // 11,796,480
#define OUT2_ELEMS ((size_t)N_ * H_ * W_ * K_)      //    165,888

typedef float f4 __attribute__((ext_vector_type(4)));

__global__ __launch_bounds__(BLK) void dynconv_strip(
    const float* __restrict__ q,
    const float* __restrict__ df,
    float* __restrict__ out)
{
    const int t  = threadIdx.x;          // 0..575
    const int w4 = t % 12;               // strip index along W
    const int h  = t / 12;               // 0..47
    const int w0 = w4 * 4;

    const int b     = blockIdx.x;        // 0..511
    const int chunk = b % NCHUNK;        // consecutive blocks share n -> df L2 reuse
    const int n     = b / NCHUNK;
    const int c0    = chunk * CH;

    // ---- zero out2 (folded in; replaces separate memset dispatch) ----
    {
        size_t g = (size_t)b * BLK + t;
        if (g < OUT2_ELEMS) out[OUT1_ELEMS + g] = 0.f;
    }

    // ---- per-pixel filter taps: 4 pixels x 9 taps = 36 contiguous floats,
    //      base offset is a multiple of 144 B -> 9 aligned float4 loads ----
    float f[36];
    {
        const f4* dfp = (const f4*)(df + ((size_t)(n * (H_ * W_) + h * W_ + w0)) * K_);
#pragma unroll
        for (int i = 0; i < 9; ++i) {
            f4 v = dfp[i];
            f[4*i+0] = v.x; f[4*i+1] = v.y; f[4*i+2] = v.z; f[4*i+3] = v.w;
        }
    }

    const size_t plane = (size_t)H_ * W_;
    // row-clamped offsets for dy = 0,1,2  (row = h+dy-1; invalid -> row 0, zeroed later)
    int roff[3];
    bool rv[3];
#pragma unroll
    for (int dy = 0; dy < 3; ++dy) {
        int row = h + dy - 1;
        rv[dy]  = (row >= 0) && (row < H_);
        roff[dy] = rv[dy] ? (dy - 1) * W_ : -h * W_;   // clamp to row 0 of this plane
    }

    const float* qbase = q   + ((size_t)(n * C_ + c0) * plane) + (size_t)h * W_ + w0;
    float*       obase = out + ((size_t)(n * C_ + c0) * plane) + (size_t)h * W_ + w0;

#pragma unroll 2
    for (int ci = 0; ci < CH; ++ci) {
        const float* qp = qbase + (size_t)ci * plane;
        f4 acc = (f4){0.f, 0.f, 0.f, 0.f};

#pragma unroll
        for (int dy = 0; dy < 3; ++dy) {
            f4 m = *(const f4*)(qp + roff[dy]);                    // aligned 16B
            float lft = (w4 > 0)  ? qp[roff[dy] - 1] : 0.f;        // exec-masked
            float rgt = (w4 < 11) ? qp[roff[dy] + 4] : 0.f;
            if (!rv[dy]) { m = (f4){0.f,0.f,0.f,0.f}; lft = 0.f; rgt = 0.f; }

            const int fb = dy * 3;
            acc.x = fmaf(f[ 0 + fb], lft, acc.x);
            acc.x = fmaf(f[ 1 + fb], m.x, acc.x);
            acc.x = fmaf(f[ 2 + fb], m.y, acc.x);

            acc.y = fmaf(f[ 9 + fb], m.x, acc.y);
            acc.y = fmaf(f[10 + fb], m.y, acc.y);
            acc.y = fmaf(f[11 + fb], m.z, acc.y);

            acc.z = fmaf(f[18 + fb], m.y, acc.z);
            acc.z = fmaf(f[19 + fb], m.z, acc.z);
            acc.z = fmaf(f[20 + fb], m.w, acc.z);

            acc.w = fmaf(f[27 + fb], m.z, acc.w);
            acc.w = fmaf(f[28 + fb], m.w, acc.w);
            acc.w = fmaf(f[29 + fb], rgt, acc.w);
        }

        acc.x = fmaxf(acc.x, 0.f);
        acc.y = fmaxf(acc.y, 0.f);
        acc.z = fmaxf(acc.z, 0.f);
        acc.w = fmaxf(acc.w, 0.f);
        *(f4*)(obase + (size_t)ci * plane) = acc;
    }
}

extern "C" void kernel_launch(void* const* d_in, const int* in_sizes, int n_in,
                              void* d_out, int out_size, void* d_ws, size_t ws_size,
                              hipStream_t stream)
{
    const float* q  = (const float*)d_in[0];
    const float* df = (const float*)d_in[1];
    float* out = (float*)d_out;

    const int blocks = N_ * NCHUNK;   // 512
    dynconv_strip<<<blocks, BLK, 0, stream>>>(q, df, out);
}